// Round 1
// 239.818 us; speedup vs baseline: 1.0079x; 1.0079x over previous
//
#include <hip/hip_runtime.h>

// QKV attention: qkv [B=64, 3*64, T=2048] fp32 -> out [64, 64, 2048] fp32.
// Round 8 changes vs round 7 (241.7 us, attn 99 us):
//  - BQ 256->128 (wave owns 32 q-rows): LDS 55296->32768 B -> 4 blocks/CU
//    (was 2), grid 512->1024 blocks. Occupancy 19.6% -> ~39% target.
//  - LDS XOR swizzle (rows 64 fp16 = 128 B, col ^= (row&7)<<3, 16B granule)
//    on Ks/Vs/Pt write+read, replacing LDA=72 pad. Targets the 1.05e7
//    SQ_LDS_BANK_CONFLICT cycles (~17% of attn CU-cycles).
//  - exp -> exp2: sqrt(log2 e) folded into prep scale, v_exp_f32 direct.
//  - prep_qk + prep_v fused into one kernel (3 -> 2 launches).
// Structure otherwise identical to the verified round-2 loop (2 barriers,
// single K/V buffer, one-tile-ahead register prefetch).
// NOTE: v_cvt_pk_bf16_f32 inline asm proven wrong on HW (r3/4/5) - banned.

#define DHEAD 64
#define TLEN  2048
#define NB    64
#define BQ    128     // queries per block (wave owns 32)
#define BK    64      // keys per tile
#define LDT   65      // prep fp32 transpose leading dim (2 lanes/bank = free)

typedef _Float16 h16x8 __attribute__((ext_vector_type(8)));
typedef _Float16 h16x4 __attribute__((ext_vector_type(4)));
typedef _Float16 h16x2 __attribute__((ext_vector_type(2)));
typedef __fp16   fp16x2 __attribute__((ext_vector_type(2)));
typedef float f32x4 __attribute__((ext_vector_type(4)));

// 1/sqrt(sqrt(64)) * sqrt(log2(e)): scores arrive pre-scaled for exp2.
#define QK_SCALE 0.42466090267246895f

extern "C" __device__ float __ocml_native_exp2_f32(float);

__device__ __forceinline__ h16x2 pkrtz(float a, float b) {
    union { fp16x2 f; h16x2 h; } u;
    u.f = __builtin_amdgcn_cvt_pkrtz(a, b);   // v_cvt_pkrtz_f16_f32
    return u.h;
}

// XOR-swizzled LDS element offset: rows of 64 fp16 (128 B), 16B-granule
// swizzle. Same key on write and read of the same row => consistent.
__device__ __forceinline__ int swz(int row, int col) {
    return row * 64 + (col ^ ((row & 7) << 3));
}

// ---------- fused prep ----------
// bx < 64 : Q/K transpose+convert, tensor = bx>>5, tile = bx&31 (64 t-cols)
// bx >= 64: V streaming convert, tile = bx-64 (64 t-cols)
__global__ __launch_bounds__(256)
void prep(const float* __restrict__ qkv, _Float16* __restrict__ ws) {
    __shared__ float T32[64 * LDT];
    const int bx = blockIdx.x, b = blockIdx.y;
    const int tid = threadIdx.x;

    if (bx < 64) {
        const int tensor = bx >> 5, tile = bx & 31;
        const float* src = qkv + ((size_t)b * 3 + tensor) * DHEAD * TLEN + tile * 64;
        _Float16* dst = ws + (size_t)tensor * NB * DHEAD * TLEN
                      + (size_t)b * DHEAD * TLEN + (size_t)tile * 64 * DHEAD;
        {
            int c = tid >> 4, t4 = (tid & 15) * 4;
            #pragma unroll
            for (int rr = 0; rr < 4; ++rr, c += 16) {
                float4 f = *(const float4*)(src + c * TLEN + t4);
                T32[(t4 + 0) * LDT + c] = f.x;
                T32[(t4 + 1) * LDT + c] = f.y;
                T32[(t4 + 2) * LDT + c] = f.z;
                T32[(t4 + 3) * LDT + c] = f.w;
            }
        }
        __syncthreads();
        #pragma unroll
        for (int rep = 0; rep < 2; ++rep) {
            int idx = rep * 256 + tid;
            int t = idx >> 3, j = idx & 7;
            const float* row = &T32[t * LDT + j * 8];
            union { h16x8 v; h16x2 h[4]; } o;
            o.h[0] = pkrtz(row[0] * QK_SCALE, row[1] * QK_SCALE);
            o.h[1] = pkrtz(row[2] * QK_SCALE, row[3] * QK_SCALE);
            o.h[2] = pkrtz(row[4] * QK_SCALE, row[5] * QK_SCALE);
            o.h[3] = pkrtz(row[6] * QK_SCALE, row[7] * QK_SCALE);
            *(h16x8*)(dst + t * DHEAD + j * 8) = o.v;
        }
    } else {
        const int tile = bx - 64;
        const float* src = qkv + ((size_t)b * 3 + 2) * DHEAD * TLEN + tile * 64;
        _Float16* dst = ws + (size_t)2 * NB * DHEAD * TLEN
                      + (size_t)b * DHEAD * TLEN + tile * 64;
        int c = tid >> 3, t8 = (tid & 7) * 8;
        #pragma unroll
        for (int rr = 0; rr < 2; ++rr, c += 32) {
            float4 f0 = *(const float4*)(src + c * TLEN + t8);
            float4 f1 = *(const float4*)(src + c * TLEN + t8 + 4);
            union { h16x8 v; h16x2 h[4]; } o;
            o.h[0] = pkrtz(f0.x, f0.y);
            o.h[1] = pkrtz(f0.z, f0.w);
            o.h[2] = pkrtz(f1.x, f1.y);
            o.h[3] = pkrtz(f1.z, f1.w);
            *(h16x8*)(dst + c * TLEN + t8) = o.v;
        }
    }
}

// ---------- attention ----------
__global__ __launch_bounds__(256, 4)
void attn(const _Float16* __restrict__ ws, float* __restrict__ out) {
    __shared__ alignas(16) _Float16 Ks[64 * 64];      // [s][c], swizzled
    __shared__ alignas(16) _Float16 Vs[64 * 64];      // [c][s], swizzled
    __shared__ alignas(16) _Float16 Pt[4][32 * 64];   // per-wave [t][s], swizzled

    const int tid  = threadIdx.x;
    const int wave = tid >> 6;
    const int lane = tid & 63;
    const int quad = lane >> 4;
    const int c16  = lane & 15;

    const int b  = blockIdx.y;
    const int t0 = blockIdx.x * BQ;

    const _Float16* qt = ws + (size_t)b * DHEAD * TLEN + (size_t)(t0 + wave * 32) * DHEAD;
    const _Float16* kt = ws + (size_t)NB * DHEAD * TLEN + (size_t)b * DHEAD * TLEN;
    const _Float16* vd = ws + (size_t)2 * NB * DHEAD * TLEN + (size_t)b * DHEAD * TLEN;

    // Hoisted Q B-frags (loop-invariant): B[k=c][n=t]
    h16x8 qf[2][2];
    #pragma unroll
    for (int ts = 0; ts < 2; ++ts)
        #pragma unroll
        for (int kk = 0; kk < 2; ++kk)
            qf[ts][kk] = *(const h16x8*)(qt + (size_t)(ts * 16 + c16) * DHEAD + kk * 32 + quad * 8);

    f32x4 acco[4][2];
    #pragma unroll
    for (int i = 0; i < 4; ++i)
        #pragma unroll
        for (int j = 0; j < 2; ++j) acco[i][j] = f32x4{0.f, 0.f, 0.f, 0.f};
    float lp[2] = {0.f, 0.f};

    _Float16* Pw = Pt[wave];

    // one-tile-ahead prefetch registers
    h16x8 kc[2], vc[2];
    #pragma unroll
    for (int r = 0; r < 2; ++r) {
        int id = tid + r * 256;
        kc[r] = *(const h16x8*)(kt + (size_t)id * 8);
        vc[r] = *(const h16x8*)(vd + (size_t)(id >> 3) * TLEN + (id & 7) * 8);
    }

    for (int it = 0; it < TLEN / BK; ++it) {
        __syncthreads();   // prior tile reads done
        #pragma unroll
        for (int r = 0; r < 2; ++r) {
            int id = tid + r * 256;
            int row = id >> 3, col = (id & 7) * 8;
            *(h16x8*)(&Ks[swz(row, col)]) = kc[r];
            *(h16x8*)(&Vs[swz(row, col)]) = vc[r];
        }
        __syncthreads();

        if (it + 1 < TLEN / BK) {
            int s0 = (it + 1) * BK;
            #pragma unroll
            for (int r = 0; r < 2; ++r) {
                int id = tid + r * 256;
                kc[r] = *(const h16x8*)(kt + (size_t)s0 * DHEAD + id * 8);
                vc[r] = *(const h16x8*)(vd + (size_t)(id >> 3) * TLEN + s0 + (id & 7) * 8);
            }
        }

        // ---- S^T = K^T Q : D[m=s][n=t] (scores arrive pre-scaled, log2e folded) ----
        f32x4 accs[4][2];
        #pragma unroll
        for (int i = 0; i < 4; ++i)
            #pragma unroll
            for (int j = 0; j < 2; ++j) accs[i][j] = f32x4{0.f, 0.f, 0.f, 0.f};
        #pragma unroll
        for (int kk = 0; kk < 2; ++kk)
            #pragma unroll
            for (int st = 0; st < 4; ++st) {
                h16x8 ka = *(const h16x8*)(&Ks[swz(st * 16 + c16, kk * 32 + quad * 8)]);
                #pragma unroll
                for (int ts = 0; ts < 2; ++ts)
                    accs[st][ts] = __builtin_amdgcn_mfma_f32_16x16x32_f16(ka, qf[ts][kk], accs[st][ts], 0, 0, 0);
            }

        // ---- softmax numerator via exp2 (scale pre-folded); store P^T[t][s] ----
        // C layout: lane holds S^T[s = st*16+quad*4+r][t = ts*16+c16]
        #pragma unroll
        for (int st = 0; st < 4; ++st)
            #pragma unroll
            for (int ts = 0; ts < 2; ++ts) {
                f32x4 v = accs[st][ts];
                float e0 = __ocml_native_exp2_f32(v[0]);
                float e1 = __ocml_native_exp2_f32(v[1]);
                float e2 = __ocml_native_exp2_f32(v[2]);
                float e3 = __ocml_native_exp2_f32(v[3]);
                lp[ts] += (e0 + e1) + (e2 + e3);
                union { h16x4 v4; h16x2 h[2]; } p;
                p.h[0] = pkrtz(e0, e1);
                p.h[1] = pkrtz(e2, e3);
                *(h16x4*)(&Pw[swz(ts * 16 + c16, st * 16 + quad * 4)]) = p.v4;
            }

        // ---- O^T += V P^T : A = Vs rows, B = Pt rows (wave-private round-trip) ----
        #pragma unroll
        for (int kk = 0; kk < 2; ++kk) {
            h16x8 pb[2];
            #pragma unroll
            for (int ts = 0; ts < 2; ++ts)
                pb[ts] = *(const h16x8*)(&Pw[swz(ts * 16 + c16, kk * 32 + quad * 8)]);
            #pragma unroll
            for (int cst = 0; cst < 4; ++cst) {
                h16x8 va = *(const h16x8*)(&Vs[swz(cst * 16 + c16, kk * 32 + quad * 8)]);
                #pragma unroll
                for (int ts = 0; ts < 2; ++ts)
                    acco[cst][ts] = __builtin_amdgcn_mfma_f32_16x16x32_f16(va, pb[ts], acco[cst][ts], 0, 0, 0);
            }
        }
    }

    // ---- finalize: row sums split across lanes l, l^16, l^32 ----
    float rinv[2];
    #pragma unroll
    for (int ts = 0; ts < 2; ++ts) {
        float l = lp[ts];
        l += __shfl_xor(l, 16);
        l += __shfl_xor(l, 32);
        rinv[ts] = 1.0f / l;
    }

    // O^T C layout: lane holds O^T[c=cst*16+quad*4+r][t=ts*16+c16]
    float* ob = out + (size_t)b * DHEAD * TLEN + t0 + wave * 32;
    #pragma unroll
    for (int cst = 0; cst < 4; ++cst)
        #pragma unroll
        for (int ts = 0; ts < 2; ++ts)
            #pragma unroll
            for (int r = 0; r < 4; ++r)
                ob[(size_t)(cst * 16 + quad * 4 + r) * TLEN + ts * 16 + c16] = acco[cst][ts][r] * rinv[ts];
}

extern "C" void kernel_launch(void* const* d_in, const int* in_sizes, int n_in,
                              void* d_out, int out_size, void* d_ws, size_t ws_size,
                              hipStream_t stream) {
    const float* qkv = (const float*)d_in[0];
    _Float16* ws = (_Float16*)d_ws;
    float* out = (float*)d_out;
    // ws: Qt | Kt | V, fp16, 3 * 64 * 64 * 2048 * 2 B = 50.3 MB
    prep<<<dim3(96, NB), 256, 0, stream>>>(qkv, ws);
    attn<<<dim3(TLEN / BQ, NB), 256, 0, stream>>>(ws, out);
}